// Round 17
// baseline (106.869 us; speedup 1.0000x reference)
//
#include <hip/hip_runtime.h>
#include <hip/hip_bf16.h>
#include <math.h>

#define NTOK  16384
#define INF   2048
#define OUTF  2048
#define SR    45
#define RANK  8
#define BLK   64
#define NBLK  32
#define NRULE 256
#define NHIST 32
#define MAXSLOT (NTOK + NRULE * 15)   // 20224
#define NTILE16 (MAXSLOT / 16)        // 1264 tiles of 16 slots

typedef __attribute__((ext_vector_type(8))) short bf16x8;
typedef __attribute__((ext_vector_type(4))) float f32x4;
typedef __attribute__((ext_vector_type(4))) short s16x4;

typedef const __attribute__((address_space(1))) unsigned int GU32;
typedef __attribute__((address_space(3))) unsigned int LU32;

#define MFMA __builtin_amdgcn_mfma_f32_16x16x32_bf16
#define SBAR() __builtin_amdgcn_sched_barrier(0)

#define VMCNT(n) do { asm volatile("s_waitcnt vmcnt(" #n ")" ::: "memory"); \
                      __builtin_amdgcn_sched_barrier(0); } while (0)
#define GLOAD(dst, ptr) \
    asm volatile("global_load_dwordx4 %0, %1, off" : "=v"(dst) : "v"(ptr) : "memory")

__device__ inline short f2bs(float f) {
    __hip_bfloat16 h = __float2bfloat16(f);
    return *reinterpret_cast<short*>(&h);
}
__device__ inline bf16x8 cvt8(const float4& a, const float4& b) {
    bf16x8 r;
    r[0] = f2bs(a.x); r[1] = f2bs(a.y); r[2] = f2bs(a.z); r[3] = f2bs(a.w);
    r[4] = f2bs(b.x); r[5] = f2bs(b.y); r[6] = f2bs(b.z); r[7] = f2bs(b.w);
    return r;
}

// ---------------------------------------------------------------------------
// prep A: blocks 0..127 pack weights into MFMA B-frag layout (bf16);
//         blocks 128..159 per-block histogram slabs + init perm/srid.
// ---------------------------------------------------------------------------
__global__ void kprep_a(const int* __restrict__ rule_ids,
                        const float* __restrict__ shared_in,
                        const float* __restrict__ shared_out,
                        const float* __restrict__ rule_in,
                        const float* __restrict__ rule_out,
                        unsigned short* __restrict__ ssb,   // [64k32][3nf][64][8]
                        unsigned short* __restrict__ sob,   // [128CF][2kc][64][8]
                        unsigned short* __restrict__ rinf,  // [256][2half][64][8]
                        unsigned short* __restrict__ rof,   // [256][4cf][64][8]
                        int* __restrict__ ghist_part,
                        int* __restrict__ perm_p,
                        int* __restrict__ srid_p)
{
    if (blockIdx.x < 128) {
        const int tid = blockIdx.x * 256 + threadIdx.x;
        const int stride = 128 * 256;
        for (int idx = tid; idx < 64 * 3 * 512; idx += stride) {
            int ch = idx / 1536, rem = idx - ch * 1536;
            int nf = rem / 512;
            int l = (rem >> 3) & 63, j = idx & 7;
            int k = ch * 32 + ((l >> 4) << 3) + j;
            int col = nf * 16 + (l & 15);
            ssb[idx] = (col < SR) ? (unsigned short)f2bs(shared_in[(size_t)k * SR + col]) : 0;
        }
        for (int idx = tid; idx < 128 * 2 * 512; idx += stride) {
            int CF = idx >> 10;
            int kc = (idx >> 9) & 1;
            int l = (idx >> 3) & 63, j = idx & 7;
            int k = kc * 32 + ((l >> 4) << 3) + j;
            int col = CF * 16 + (l & 15);
            sob[idx] = (k < SR) ? (unsigned short)f2bs(shared_out[(size_t)k * OUTF + col]) : 0;
        }
        for (int idx = tid; idx < NRULE * 2 * 512; idx += stride) {
            int rid = idx >> 10;
            int half = (idx >> 9) & 1;
            int l = (idx >> 3) & 63, j = idx & 7;
            int r = l & 15;
            int s = half * 32 + ((l >> 4) << 3) + j;
            rinf[idx] = (r < RANK) ? (unsigned short)f2bs(rule_in[(size_t)rid * 512 + s * RANK + r]) : 0;
        }
        for (int idx = tid; idx < NRULE * 4 * 512; idx += stride) {
            int rid = idx >> 11;
            int cf = (idx >> 9) & 3;
            int l = (idx >> 3) & 63, j = idx & 7;
            int k = ((l >> 4) << 3) + j;
            int c = cf * 16 + (l & 15);
            rof[idx] = (k < RANK) ? (unsigned short)f2bs(rule_out[(size_t)rid * 512 + k * BLK + c]) : 0;
        }
    } else {
        __shared__ int lh[NRULE];
        const int tid = threadIdx.x;
        const int hb = blockIdx.x - 128;
        lh[tid] = 0;
        __syncthreads();
        const int base = hb * 512;
        atomicAdd(&lh[rule_ids[base + tid]], 1);
        atomicAdd(&lh[rule_ids[base + 256 + tid]], 1);
        __syncthreads();
        ghist_part[hb * NRULE + tid] = lh[tid];
        for (int j = tid; j < MAXSLOT / 32; j += 256) {
            int idx = hb * (MAXSLOT / 32) + j;
            perm_p[idx] = -1;
            srid_p[idx] = 0;
        }
    }
}

__global__ void kprep_scan(const int* __restrict__ ghist_part,
                           const float* __restrict__ logits,
                           int* __restrict__ gcnt,
                           int* __restrict__ srid_p,
                           float* __restrict__ sel_t,
                           int* __restrict__ ntot)
{
    __shared__ int sc[NRULE];
    const int tid = threadIdx.x;
    int h = 0;
#pragma unroll
    for (int b = 0; b < NHIST; ++b) h += ghist_part[b * NRULE + tid];
    const int pd = (h + 15) & ~15;
    sc[tid] = pd;
    for (int off = 1; off < NRULE; off <<= 1) {
        __syncthreads();
        int v = (tid >= off) ? sc[tid - off] : 0;
        __syncthreads();
        sc[tid] += v;
    }
    __syncthreads();
    const int excl = sc[tid] - pd;
    gcnt[tid] = excl;
    for (int q = h; q < pd; ++q) srid_p[excl + q] = tid;
    if (tid == NRULE - 1) *ntot = sc[tid];
    const float invT = 5.65685424949238f;
    const float* __restrict__ lg = logits + (size_t)tid * NBLK;
    float m = -1e30f;
    for (int b = 0; b < NBLK; ++b) m = fmaxf(m, lg[b] * invT);
    float s = 0.0f;
    for (int b = 0; b < NBLK; ++b) s += expf(lg[b] * invT - m);
    const float inv = 1.0f / s;
    for (int b = 0; b < NBLK; ++b)
        sel_t[(size_t)tid * NBLK + b] = expf(lg[b] * invT - m) * inv;
}

__global__ void kprep_scatter(const int* __restrict__ rule_ids,
                              int* __restrict__ gcnt,
                              int* __restrict__ perm_p,
                              int* __restrict__ srid_p)
{
    const int i = blockIdx.x * 256 + threadIdx.x;
    const int r = rule_ids[i];
    const int p = atomicAdd(&gcnt[r], 1);
    perm_p[p] = i;
    srid_p[p] = r;
}

// ---------------------------------------------------------------------------
// kmain (fused): 16 slots, 128 thr = 2 waves. Wave w owns K-half w PRIVATELY:
//   own 2x4KB LDS ring (global_load_lds), own asm weight loads, exact
//   per-wave vmcnt(10) depth-2 ledger, ZERO barriers across all 16 chunks
//   (R16-k1 phase 1, which passed). Hidden is chunk-local -> written straight
//   to hs_lds (wave-disjoint columns). 3 barriers total, then R12's proven
//   64-qi phase-2 SBAR ring with predicated stores. No global round-trip.
// LDS 26.5 KB. Grid 1264 (grid-limited ~2.5 waves/SIMD -> launch_bounds(,3)).
// ---------------------------------------------------------------------------
__global__ __launch_bounds__(128, 3)
void kmain(const float* __restrict__ x,
           const int* __restrict__ perm_p,
           const int* __restrict__ srid_p,
           const unsigned short* __restrict__ ssb,
           const unsigned short* __restrict__ sob,
           const unsigned short* __restrict__ rinf,
           const unsigned short* __restrict__ rof,
           const float* __restrict__ sel_t,
           const int* __restrict__ ntot,
           float* __restrict__ out)
{
    __shared__ __align__(16) char xq[2][8192];                // [wave][2 slot][4KB]
    __shared__ __align__(16) unsigned short hs_lds[16][264];  // 8.25 KB
    __shared__ __align__(16) unsigned short t_bf[16][72];     // 2.25 KB

#define TRD(W, SL, C) (((float*)xq)[((W) * 16 + (SL)) * 52 + (C)])

    const int slot0 = blockIdx.x * 16;
    if (slot0 >= *ntot) return;

    const int tid  = threadIdx.x;       // 0..127
    const int lane = tid & 63;
    const int w    = tid >> 6;          // K-half (ph1) / col-half (ph2)
    const int row_l = lane & 15, grp = lane >> 4;
    const int cbase = w * 16;           // wave's first 64-col chunk

    const int rid_u = __builtin_amdgcn_readfirstlane(srid_p[slot0]);

    // per-lane staging sources: instr v stages rows 4v + (lane>>4), unit lane&15
    const char* gsrc0; const char* gsrc1; const char* gsrc2; const char* gsrc3;
    {
        const int u = lane & 15;
        const char* t[4];
#pragma unroll
        for (int v = 0; v < 4; ++v) {
            const int row = 4 * v + (lane >> 4);
            int tok = perm_p[slot0 + row];
            if (tok < 0) tok = 0;
            t[v] = (const char*)(x + (size_t)tok * INF) + ((u ^ (row & 7)) << 4);
        }
        gsrc0 = t[0]; gsrc1 = t[1]; gsrc2 = t[2]; gsrc3 = t[3];
    }

    const bf16x8 ri0 = *(const bf16x8*)(rinf + ((size_t)rid_u * 2 + 0) * 512 + lane * 8);
    const bf16x8 ri1 = *(const bf16x8*)(rinf + ((size_t)rid_u * 2 + 1) * 512 + lane * 8);
    float sel16[16];
#pragma unroll
    for (int ci = 0; ci < 16; ++ci)
        sel16[ci] = sel_t[(size_t)rid_u * NBLK + cbase + ci];

    // ds_read byte offsets (XOR-swizzled) within one 4KB slot
    const int swz = row_l & 7;
    const int off00 = row_l * 256 + (((0 + grp * 2 + 0) ^ swz) << 4);
    const int off01 = row_l * 256 + (((0 + grp * 2 + 1) ^ swz) << 4);
    const int off10 = row_l * 256 + (((8 + grp * 2 + 0) ^ swz) << 4);
    const int off11 = row_l * 256 + (((8 + grp * 2 + 1) ^ swz) << 4);

    f32x4 aT0 = {0.f, 0.f, 0.f, 0.f};
    f32x4 aT1 = {0.f, 0.f, 0.f, 0.f};
    f32x4 aT2 = {0.f, 0.f, 0.f, 0.f};
    bf16x8 wreg[2][6];

    char* const xw = xq[w];             // wave's private 8KB region

#define STAGE(SL, CI) do { \
        char* _lb = xw + ((SL) << 12); \
        const size_t _o = (size_t)(cbase + (CI)) << 8; \
        __builtin_amdgcn_global_load_lds((GU32*)(gsrc0 + _o), (LU32*)_lb,          16, 0, 0); \
        __builtin_amdgcn_global_load_lds((GU32*)(gsrc1 + _o), (LU32*)(_lb + 1024), 16, 0, 0); \
        __builtin_amdgcn_global_load_lds((GU32*)(gsrc2 + _o), (LU32*)(_lb + 2048), 16, 0, 0); \
        __builtin_amdgcn_global_load_lds((GU32*)(gsrc3 + _o), (LU32*)(_lb + 3072), 16, 0, 0); \
    } while (0)

#define WLOAD(SL, CI) do { \
        const unsigned short* _w0 = ssb + (size_t)((cbase + (CI)) * 2) * 1536 + lane * 8; \
        GLOAD(wreg[SL][0], _w0); \
        GLOAD(wreg[SL][1], _w0 + 512); \
        GLOAD(wreg[SL][2], _w0 + 1024); \
        GLOAD(wreg[SL][3], _w0 + 1536); \
        GLOAD(wreg[SL][4], _w0 + 2048); \
        GLOAD(wreg[SL][5], _w0 + 2560); \
    } while (0)

    VMCNT(0);                           // ledger starts clean

    STAGE(0, 0); WLOAD(0, 0);           // batch0: 10 ops
    STAGE(1, 1); WLOAD(1, 1);           // batch1: 10 ops

#pragma unroll
    for (int ci = 0; ci < 16; ++ci) {
        if (ci < 15) { VMCNT(10); } else { VMCNT(0); }   // batch(ci) landed
        const int sl = ci & 1;
        const char* xb = xw + (sl << 12);
        f32x4 aH = {0.f, 0.f, 0.f, 0.f};
        {
            const float4 fa0 = *(const float4*)(xb + off00);
            const float4 fa1 = *(const float4*)(xb + off01);
            const bf16x8 af0 = cvt8(fa0, fa1);
            aT0 = MFMA(af0, wreg[sl][0], aT0, 0, 0, 0);
            aT1 = MFMA(af0, wreg[sl][1], aT1, 0, 0, 0);
            aT2 = MFMA(af0, wreg[sl][2], aT2, 0, 0, 0);
            aH  = MFMA(af0, ri0, aH, 0, 0, 0);
            const float4 fb0 = *(const float4*)(xb + off10);
            const float4 fb1 = *(const float4*)(xb + off11);
            const bf16x8 af1 = cvt8(fb0, fb1);
            aT0 = MFMA(af1, wreg[sl][3], aT0, 0, 0, 0);
            aT1 = MFMA(af1, wreg[sl][4], aT1, 0, 0, 0);
            aT2 = MFMA(af1, wreg[sl][5], aT2, 0, 0, 0);
            aH  = MFMA(af1, ri1, aH, 0, 0, 0);
        }
        if (row_l < RANK) {             // hidden: chunk-local, wave-disjoint cols
            const int c = cbase + ci;
#pragma unroll
            for (int q = 0; q < 4; ++q)
                hs_lds[(grp << 2) + q][c * 8 + row_l] =
                    (unsigned short)f2bs(aH[q] * sel16[ci]);
        }
        if (ci < 14) { STAGE(sl, ci + 2); WLOAD(sl, ci + 2); }
    }

    // ---- t partials -> tred (xq overlay), reduce K-halves -> t_bf ---------
    __syncthreads();                    // both waves done with their rings
#pragma unroll
    for (int q = 0; q < 4; ++q) {
        const int sl = (grp << 2) + q;
        TRD(w, sl, row_l)      = aT0[q];
        TRD(w, sl, 16 + row_l) = aT1[q];
        TRD(w, sl, 32 + row_l) = aT2[q];
    }
    __syncthreads();
    {
        const int sl = tid >> 3;        // 0..15
        const int cidx = tid & 7;
        if (cidx < 6) {
            const int c0 = cidx << 3;
            s16x4 v0, v1;
#pragma unroll
            for (int j = 0; j < 4; ++j) {
                v0[j] = f2bs(TRD(0, sl, c0 + j)     + TRD(1, sl, c0 + j));
                v1[j] = f2bs(TRD(0, sl, c0 + 4 + j) + TRD(1, sl, c0 + 4 + j));
            }
            *(s16x4*)(&t_bf[sl][c0])     = v0;
            *(s16x4*)(&t_bf[sl][c0 + 4]) = v1;
        } else {
            const int c0 = 48 + ((cidx - 6) << 3);
            const s16x4 z = {0, 0, 0, 0};
            *(s16x4*)(&t_bf[sl][c0])     = z;
            *(s16x4*)(&t_bf[sl][c0 + 4]) = z;
        }
    }
    __syncthreads();

    // ================= phase 2: out = t@shared_out + hs@rule_out ===========
    {
        const int p = w;                // col-half: [p*1024, +1024)
        const bf16x8 at0 = *(const bf16x8*)(&t_bf[row_l][grp << 3]);
        const bf16x8 at1 = *(const bf16x8*)(&t_bf[row_l][32 + (grp << 3)]);

        bf16x8 rfv[4];
#pragma unroll
        for (int i = 0; i < 4; ++i)
            rfv[i] = *(const bf16x8*)(rof + ((size_t)rid_u * 4 + i) * 512 + lane * 8);

        const int4 pv = *(const int4*)(perm_p + slot0 + (grp << 2));
        float* const orow0 = out + (size_t)(pv.x < 0 ? 0 : pv.x) * OUTF;
        float* const orow1 = out + (size_t)(pv.y < 0 ? 0 : pv.y) * OUTF;
        float* const orow2 = out + (size_t)(pv.z < 0 ? 0 : pv.z) * OUTF;
        float* const orow3 = out + (size_t)(pv.w < 0 ? 0 : pv.w) * OUTF;

        const int CF0 = p * 64;
        const int bb0 = p * 16;
        const unsigned short* __restrict__ sobw = sob + (size_t)CF0 * 1024 + lane * 8;

        bf16x8 sb[4][2];
        bf16x8 ah[2];
        const bf16x8 zz = {0, 0, 0, 0, 0, 0, 0, 0};

#define LOADQ(SL, QI) do { \
        const unsigned short* _sp = sobw + (size_t)(QI) * 1024; \
        sb[SL][0] = *(const bf16x8*)(_sp); \
        sb[SL][1] = *(const bf16x8*)(_sp + 512); \
    } while (0)
#define LOADA(SL, BI) do { \
        ah[SL] = zz; \
        if (lane < 16) \
            ah[SL] = *(const bf16x8*)(&hs_lds[lane][(bb0 + (BI)) * 8]); \
    } while (0)

        LOADQ(0, 0); LOADQ(1, 1); LOADQ(2, 2);
        LOADA(0, 0);
        SBAR();

#pragma unroll
        for (int qi = 0; qi < 64; ++qi) {
            if (qi < 61) LOADQ((qi + 3) & 3, qi + 3);
            if ((qi & 3) == 0 && qi < 60) LOADA(((qi >> 2) + 1) & 1, (qi >> 2) + 1);
            SBAR();
            f32x4 acc = {0.f, 0.f, 0.f, 0.f};
            acc = MFMA(at0, sb[qi & 3][0], acc, 0, 0, 0);
            acc = MFMA(at1, sb[qi & 3][1], acc, 0, 0, 0);
            acc = MFMA(ah[(qi >> 2) & 1], rfv[qi & 3], acc, 0, 0, 0);
            const int col = ((CF0 + qi) << 4) + row_l;
            if (pv.x >= 0) orow0[col] = acc[0];
            if (pv.y >= 0) orow1[col] = acc[1];
            if (pv.z >= 0) orow2[col] = acc[2];
            if (pv.w >= 0) orow3[col] = acc[3];
            SBAR();
        }
#undef LOADQ
#undef LOADA
    }
}

extern "C" void kernel_launch(void* const* d_in, const int* in_sizes, int n_in,
                              void* d_out, int out_size, void* d_ws, size_t ws_size,
                              hipStream_t stream)
{
    const float* x          = (const float*)d_in[0];
    const int*   rule_ids   = (const int*)  d_in[1];
    const float* shared_in  = (const float*)d_in[2];
    const float* shared_out = (const float*)d_in[3];
    const float* rule_in    = (const float*)d_in[4];
    const float* rule_out   = (const float*)d_in[5];
    const float* logits     = (const float*)d_in[6];
    float* out = (float*)d_out;

    char* p = (char*)d_ws;
    auto carve = [&p](size_t bytes) {
        char* r = p;
        p += (bytes + 255) & ~(size_t)255;
        return r;
    };
    int*            perm_p = (int*)carve(MAXSLOT * 4);
    int*            srid_p = (int*)carve(MAXSLOT * 4);
    unsigned short* ssb    = (unsigned short*)carve(64 * 3 * 512 * 2);
    unsigned short* sob    = (unsigned short*)carve(128 * 2 * 512 * 2);
    unsigned short* rinf   = (unsigned short*)carve((size_t)NRULE * 2 * 512 * 2);
    unsigned short* rof    = (unsigned short*)carve((size_t)NRULE * 4 * 512 * 2);
    float*          sel_t  = (float*)carve((size_t)NRULE * NBLK * 4);
    int*            ghistp = (int*)carve((size_t)NHIST * NRULE * 4);
    int*            gcnt   = (int*)carve(NRULE * 4);
    int*            ntot   = (int*)carve(4);

    kprep_a<<<dim3(160), dim3(256), 0, stream>>>(
        rule_ids, shared_in, shared_out, rule_in, rule_out,
        ssb, sob, rinf, rof, ghistp, perm_p, srid_p);
    kprep_scan<<<dim3(1), dim3(256), 0, stream>>>(
        ghistp, logits, gcnt, srid_p, sel_t, ntot);
    kprep_scatter<<<dim3(64), dim3(256), 0, stream>>>(
        rule_ids, gcnt, perm_p, srid_p);
    kmain<<<dim3(NTILE16), dim3(128), 0, stream>>>(
        x, perm_p, srid_p, ssb, sob, rinf, rof, sel_t, ntot, out);
}

// Round 18
// 89.709 us; speedup vs baseline: 1.1913x; 1.1913x over previous
//
#include <hip/hip_runtime.h>
#include <hip/hip_bf16.h>
#include <math.h>

#define NTOK  16384
#define INF   2048
#define OUTF  2048
#define SR    45
#define RANK  8
#define BLK   64
#define NBLK  32
#define NRULE 256
#define NHIST 32
#define MAXSLOT (NTOK + NRULE * 15)   // 20224
#define NTILE16 (MAXSLOT / 16)        // 1264 tiles of 16 slots

typedef __attribute__((ext_vector_type(8))) short bf16x8;
typedef __attribute__((ext_vector_type(4))) float f32x4;
typedef __attribute__((ext_vector_type(4))) short s16x4;

typedef const __attribute__((address_space(1))) unsigned int GU32;
typedef __attribute__((address_space(3))) unsigned int LU32;

#define MFMA __builtin_amdgcn_mfma_f32_16x16x32_bf16
#define SBAR() __builtin_amdgcn_sched_barrier(0)

__device__ inline short f2bs(float f) {
    __hip_bfloat16 h = __float2bfloat16(f);
    return *reinterpret_cast<short*>(&h);
}
__device__ inline bf16x8 cvt8(const float4& a, const float4& b) {
    bf16x8 r;
    r[0] = f2bs(a.x); r[1] = f2bs(a.y); r[2] = f2bs(a.z); r[3] = f2bs(a.w);
    r[4] = f2bs(b.x); r[5] = f2bs(b.y); r[6] = f2bs(b.z); r[7] = f2bs(b.w);
    return r;
}

// ---------------------------------------------------------------------------
// prep A: blocks 0..127 pack weights into MFMA B-frag layout (bf16);
//         blocks 128..159 per-block histogram slabs + init perm/srid.
// ---------------------------------------------------------------------------
__global__ void kprep_a(const int* __restrict__ rule_ids,
                        const float* __restrict__ shared_in,
                        const float* __restrict__ shared_out,
                        const float* __restrict__ rule_in,
                        const float* __restrict__ rule_out,
                        unsigned short* __restrict__ ssb,   // [64k32][3nf][64][8]
                        unsigned short* __restrict__ sob,   // [128CF][2kc][64][8]
                        unsigned short* __restrict__ rinf,  // [256][2half][64][8]
                        unsigned short* __restrict__ rof,   // [256][4cf][64][8]
                        int* __restrict__ ghist_part,
                        int* __restrict__ perm_p,
                        int* __restrict__ srid_p)
{
    if (blockIdx.x < 128) {
        const int tid = blockIdx.x * 256 + threadIdx.x;
        const int stride = 128 * 256;
        for (int idx = tid; idx < 64 * 3 * 512; idx += stride) {
            int ch = idx / 1536, rem = idx - ch * 1536;
            int nf = rem / 512;
            int l = (rem >> 3) & 63, j = idx & 7;
            int k = ch * 32 + ((l >> 4) << 3) + j;
            int col = nf * 16 + (l & 15);
            ssb[idx] = (col < SR) ? (unsigned short)f2bs(shared_in[(size_t)k * SR + col]) : 0;
        }
        for (int idx = tid; idx < 128 * 2 * 512; idx += stride) {
            int CF = idx >> 10;
            int kc = (idx >> 9) & 1;
            int l = (idx >> 3) & 63, j = idx & 7;
            int k = kc * 32 + ((l >> 4) << 3) + j;
            int col = CF * 16 + (l & 15);
            sob[idx] = (k < SR) ? (unsigned short)f2bs(shared_out[(size_t)k * OUTF + col]) : 0;
        }
        for (int idx = tid; idx < NRULE * 2 * 512; idx += stride) {
            int rid = idx >> 10;
            int half = (idx >> 9) & 1;
            int l = (idx >> 3) & 63, j = idx & 7;
            int r = l & 15;
            int s = half * 32 + ((l >> 4) << 3) + j;
            rinf[idx] = (r < RANK) ? (unsigned short)f2bs(rule_in[(size_t)rid * 512 + s * RANK + r]) : 0;
        }
        for (int idx = tid; idx < NRULE * 4 * 512; idx += stride) {
            int rid = idx >> 11;
            int cf = (idx >> 9) & 3;
            int l = (idx >> 3) & 63, j = idx & 7;
            int k = ((l >> 4) << 3) + j;
            int c = cf * 16 + (l & 15);
            rof[idx] = (k < RANK) ? (unsigned short)f2bs(rule_out[(size_t)rid * 512 + k * BLK + c]) : 0;
        }
    } else {
        __shared__ int lh[NRULE];
        const int tid = threadIdx.x;
        const int hb = blockIdx.x - 128;
        lh[tid] = 0;
        __syncthreads();
        const int base = hb * 512;
        atomicAdd(&lh[rule_ids[base + tid]], 1);
        atomicAdd(&lh[rule_ids[base + 256 + tid]], 1);
        __syncthreads();
        ghist_part[hb * NRULE + tid] = lh[tid];
        for (int j = tid; j < MAXSLOT / 32; j += 256) {
            int idx = hb * (MAXSLOT / 32) + j;
            perm_p[idx] = -1;
            srid_p[idx] = 0;
        }
    }
}

__global__ void kprep_scan(const int* __restrict__ ghist_part,
                           const float* __restrict__ logits,
                           int* __restrict__ gcnt,
                           int* __restrict__ srid_p,
                           float* __restrict__ sel_t,
                           int* __restrict__ ntot)
{
    __shared__ int sc[NRULE];
    const int tid = threadIdx.x;
    int h = 0;
#pragma unroll
    for (int b = 0; b < NHIST; ++b) h += ghist_part[b * NRULE + tid];
    const int pd = (h + 15) & ~15;
    sc[tid] = pd;
    for (int off = 1; off < NRULE; off <<= 1) {
        __syncthreads();
        int v = (tid >= off) ? sc[tid - off] : 0;
        __syncthreads();
        sc[tid] += v;
    }
    __syncthreads();
    const int excl = sc[tid] - pd;
    gcnt[tid] = excl;
    for (int q = h; q < pd; ++q) srid_p[excl + q] = tid;
    if (tid == NRULE - 1) *ntot = sc[tid];
    const float invT = 5.65685424949238f;
    const float* __restrict__ lg = logits + (size_t)tid * NBLK;
    float m = -1e30f;
    for (int b = 0; b < NBLK; ++b) m = fmaxf(m, lg[b] * invT);
    float s = 0.0f;
    for (int b = 0; b < NBLK; ++b) s += expf(lg[b] * invT - m);
    const float inv = 1.0f / s;
    for (int b = 0; b < NBLK; ++b)
        sel_t[(size_t)tid * NBLK + b] = expf(lg[b] * invT - m) * inv;
}

__global__ void kprep_scatter(const int* __restrict__ rule_ids,
                              int* __restrict__ gcnt,
                              int* __restrict__ perm_p,
                              int* __restrict__ srid_p)
{
    const int i = blockIdx.x * 256 + threadIdx.x;
    const int r = rule_ids[i];
    const int p = atomicAdd(&gcnt[r], 1);
    perm_p[p] = i;
    srid_p[p] = r;
}

// ---------------------------------------------------------------------------
// kmain: 16 slots, 256 thr = 4 waves = (kh = w&1, par = w>>1).
// R12's proven per-round schedule at 2 chunks/round: cooperative STAGE of
// chunks {2r, 2r+1} (8 KB DMA in flight), ONE __syncthreads per round
// (16 rounds, was 32), wave (kh,par) computes sub kh of chunk 2r+par,
// hstmp merged one round behind (256 thr = both chunks). 2x waves/SIMD
// vs R12 (4.9 vs 2.47) at identical per-wave work.
// Merge: tred overlays dead xbuf; phase 2 = R14's proven col-quarter ring.
// LDS ~31 KB -> 5 blocks/CU (grid-resident).
// ---------------------------------------------------------------------------
__global__ __launch_bounds__(256, 4)
void kmain(const float* __restrict__ x,
           const int* __restrict__ perm_p,
           const int* __restrict__ srid_p,
           const unsigned short* __restrict__ ssb,
           const unsigned short* __restrict__ sob,
           const unsigned short* __restrict__ rinf,
           const unsigned short* __restrict__ rof,
           const float* __restrict__ sel_t,
           const int* __restrict__ ntot,
           float* __restrict__ out)
{
    __shared__ __align__(16) float xbuf[2][2][1024];          // 16 KB (dbuf x 2 chunks)
    __shared__ __align__(16) float hstmp[2][2][2][16][8];     // 4 KB [rbuf][par][kh]
    __shared__ __align__(16) unsigned short hs_lds[16][264];  // 8.25 KB
    __shared__ __align__(16) unsigned short t_bf[16][72];     // 2.25 KB
    __shared__ float sel_lds[NBLK];                           // 128 B

#define TRD(W, SL, C) (((float*)xbuf)[((W) * 16 + (SL)) * 52 + (C)])

    const int slot0 = blockIdx.x * 16;
    if (slot0 >= *ntot) return;

    const int tid  = threadIdx.x;       // 0..255
    const int lane = tid & 63;
    const int w    = tid >> 6;          // 0..3
    const int kh   = w & 1;             // k-sub within chunk (ph1)
    const int par  = w >> 1;            // chunk parity (ph1)
    const int row_l = lane & 15, grp = lane >> 4;

    const int rid_u = __builtin_amdgcn_readfirstlane(srid_p[slot0]);

    // staging: thread = (row = tid>>4, unit u = tid&15); XOR source swizzle
    const int srow = tid >> 4, su = tid & 15;
    int stok = perm_p[slot0 + srow];  if (stok < 0) stok = 0;
    const char* gs = (const char*)(x + (size_t)stok * INF) + ((su ^ (srow & 7)) << 4);

#define STAGE(R) do { \
        char* lb = (char*)xbuf + (((R) & 1) << 13) + ((tid >> 6) << 10); \
        __builtin_amdgcn_global_load_lds((GU32*)(gs + (size_t)(2 * (R)) * 256), \
                                         (LU32*)lb,          16, 0, 0); \
        __builtin_amdgcn_global_load_lds((GU32*)(gs + (size_t)(2 * (R) + 1) * 256), \
                                         (LU32*)(lb + 4096), 16, 0, 0); \
    } while (0)

    // ds_read offsets (XOR-swizzled) within one 4KB chunk buffer
    const int swz = row_l & 7;
    const int offA = row_l * 256 + (((kh * 8 + grp * 2 + 0) ^ swz) << 4);
    const int offB = row_l * 256 + (((kh * 8 + grp * 2 + 1) ^ swz) << 4);

    const bf16x8 ri = *(const bf16x8*)(rinf + ((size_t)rid_u * 2 + kh) * 512 + lane * 8);
    if (tid < NBLK) sel_lds[tid] = sel_t[(size_t)rid_u * NBLK + tid];

    f32x4 aT0 = {0.f, 0.f, 0.f, 0.f};
    f32x4 aT1 = {0.f, 0.f, 0.f, 0.f};
    f32x4 aT2 = {0.f, 0.f, 0.f, 0.f};

    STAGE(0);
    __syncthreads();

    for (int r = 0; r < 16; ++r) {
        if (r < 15) STAGE(r + 1);
        // merge hidden of previous round's 2 chunks (hstmp visible post-barrier)
        if (r > 0) {
            const int pb = (r - 1) & 1;
            const int mc = tid >> 7;            // chunk parity of prev round
            const int idx = tid & 127;
            const int sl = idx >> 3, rr = idx & 7;
            const int b = 2 * (r - 1) + mc;
            const float v = hstmp[pb][mc][0][sl][rr] + hstmp[pb][mc][1][sl][rr];
            hs_lds[sl][b * 8 + rr] = (unsigned short)f2bs(v * sel_lds[b]);
        }
        // compute sub kh of chunk c = 2r + par
        {
            const int c = 2 * r + par;
            const char* xb = (const char*)xbuf + ((r & 1) << 13) + (par << 12);
            const float4 fa = *(const float4*)(xb + offA);
            const float4 fb = *(const float4*)(xb + offB);
            const bf16x8 af = cvt8(fa, fb);
            const unsigned short* sp = ssb + (size_t)(c * 2 + kh) * 1536 + lane * 8;
            f32x4 aH = {0.f, 0.f, 0.f, 0.f};
            aT0 = MFMA(af, *(const bf16x8*)(sp),        aT0, 0, 0, 0);
            aT1 = MFMA(af, *(const bf16x8*)(sp + 512),  aT1, 0, 0, 0);
            aT2 = MFMA(af, *(const bf16x8*)(sp + 1024), aT2, 0, 0, 0);
            aH  = MFMA(af, ri, aH, 0, 0, 0);
            if (row_l < RANK) {
#pragma unroll
                for (int q = 0; q < 4; ++q)
                    hstmp[r & 1][par][kh][(grp << 2) + q][row_l] = aH[q];
            }
        }
        __syncthreads();                 // DMA(r+1) landed; hstmp[r] visible
    }

    // ---- epilogue: merge round 15's chunks (30, 31) ------------------------
    {
        const int pb = 1;
        const int mc = tid >> 7;
        const int idx = tid & 127;
        const int sl = idx >> 3, rr = idx & 7;
        const int b = 30 + mc;
        const float v = hstmp[pb][mc][0][sl][rr] + hstmp[pb][mc][1][sl][rr];
        hs_lds[sl][b * 8 + rr] = (unsigned short)f2bs(v * sel_lds[b]);
    }
    // ---- t partials -> tred (xbuf overlay), reduce 4 waves -> t_bf ---------
#pragma unroll
    for (int q = 0; q < 4; ++q) {
        const int sl = (grp << 2) + q;
        TRD(w, sl, row_l)      = aT0[q];
        TRD(w, sl, 16 + row_l) = aT1[q];
        TRD(w, sl, 32 + row_l) = aT2[q];
    }
    __syncthreads();
    {
        const int sl = tid >> 4;        // 0..15
        const int c0 = (tid & 15) << 2; // 0..60
        s16x4 v = {0, 0, 0, 0};
        if (c0 < 48) {
#pragma unroll
            for (int j = 0; j < 4; ++j) {
                const float sm = TRD(0, sl, c0 + j) + TRD(1, sl, c0 + j)
                               + TRD(2, sl, c0 + j) + TRD(3, sl, c0 + j);
                v[j] = f2bs(sm);
            }
        }
        *(s16x4*)(&t_bf[sl][c0]) = v;
    }
    __syncthreads();

    // ===== phase 2: out = t@shared_out + hs@rule_out (R14 col-quarter) =====
    {
        const int p = w;                // col-quarter: [p*512, +512)
        const bf16x8 at0 = *(const bf16x8*)(&t_bf[row_l][grp << 3]);
        const bf16x8 at1 = *(const bf16x8*)(&t_bf[row_l][32 + (grp << 3)]);

        bf16x8 rfv[4];
#pragma unroll
        for (int i = 0; i < 4; ++i)
            rfv[i] = *(const bf16x8*)(rof + ((size_t)rid_u * 4 + i) * 512 + lane * 8);

        const int4 pv = *(const int4*)(perm_p + slot0 + (grp << 2));
        float* const orow0 = out + (size_t)(pv.x < 0 ? 0 : pv.x) * OUTF;
        float* const orow1 = out + (size_t)(pv.y < 0 ? 0 : pv.y) * OUTF;
        float* const orow2 = out + (size_t)(pv.z < 0 ? 0 : pv.z) * OUTF;
        float* const orow3 = out + (size_t)(pv.w < 0 ? 0 : pv.w) * OUTF;

        const int CF0 = p * 32;
        const int bb0 = p * 8;
        const unsigned short* __restrict__ sobw = sob + (size_t)CF0 * 1024 + lane * 8;

        bf16x8 sb[4][2];
        bf16x8 ah[2];
        const bf16x8 zz = {0, 0, 0, 0, 0, 0, 0, 0};

#define LOADQ(SL, QI) do { \
        const unsigned short* _sp = sobw + (size_t)(QI) * 1024; \
        sb[SL][0] = *(const bf16x8*)(_sp); \
        sb[SL][1] = *(const bf16x8*)(_sp + 512); \
    } while (0)
#define LOADA(SL, BI) do { \
        ah[SL] = zz; \
        if (lane < 16) \
            ah[SL] = *(const bf16x8*)(&hs_lds[lane][(bb0 + (BI)) * 8]); \
    } while (0)

        LOADQ(0, 0); LOADQ(1, 1); LOADQ(2, 2);
        LOADA(0, 0);
        SBAR();

#pragma unroll
        for (int qi = 0; qi < 32; ++qi) {
            if (qi < 29) LOADQ((qi + 3) & 3, qi + 3);
            if ((qi & 3) == 0 && qi < 28) LOADA(((qi >> 2) + 1) & 1, (qi >> 2) + 1);
            SBAR();
            f32x4 acc = {0.f, 0.f, 0.f, 0.f};
            acc = MFMA(at0, sb[qi & 3][0], acc, 0, 0, 0);
            acc = MFMA(at1, sb[qi & 3][1], acc, 0, 0, 0);
            acc = MFMA(ah[(qi >> 2) & 1], rfv[qi & 3], acc, 0, 0, 0);
            const int col = ((CF0 + qi) << 4) + row_l;
            if (pv.x >= 0) orow0[col] = acc[0];
            if (pv.y >= 0) orow1[col] = acc[1];
            if (pv.z >= 0) orow2[col] = acc[2];
            if (pv.w >= 0) orow3[col] = acc[3];
            SBAR();
        }
#undef LOADQ
#undef LOADA
    }
}

extern "C" void kernel_launch(void* const* d_in, const int* in_sizes, int n_in,
                              void* d_out, int out_size, void* d_ws, size_t ws_size,
                              hipStream_t stream)
{
    const float* x          = (const float*)d_in[0];
    const int*   rule_ids   = (const int*)  d_in[1];
    const float* shared_in  = (const float*)d_in[2];
    const float* shared_out = (const float*)d_in[3];
    const float* rule_in    = (const float*)d_in[4];
    const float* rule_out   = (const float*)d_in[5];
    const float* logits     = (const float*)d_in[6];
    float* out = (float*)d_out;

    char* p = (char*)d_ws;
    auto carve = [&p](size_t bytes) {
        char* r = p;
        p += (bytes + 255) & ~(size_t)255;
        return r;
    };
    int*            perm_p = (int*)carve(MAXSLOT * 4);
    int*            srid_p = (int*)carve(MAXSLOT * 4);
    unsigned short* ssb    = (unsigned short*)carve(64 * 3 * 512 * 2);
    unsigned short* sob    = (unsigned short*)carve(128 * 2 * 512 * 2);
    unsigned short* rinf   = (unsigned short*)carve((size_t)NRULE * 2 * 512 * 2);
    unsigned short* rof    = (unsigned short*)carve((size_t)NRULE * 4 * 512 * 2);
    float*          sel_t  = (float*)carve((size_t)NRULE * NBLK * 4);
    int*            ghistp = (int*)carve((size_t)NHIST * NRULE * 4);
    int*            gcnt   = (int*)carve(NRULE * 4);
    int*            ntot   = (int*)carve(4);

    kprep_a<<<dim3(160), dim3(256), 0, stream>>>(
        rule_ids, shared_in, shared_out, rule_in, rule_out,
        ssb, sob, rinf, rof, ghistp, perm_p, srid_p);
    kprep_scan<<<dim3(1), dim3(256), 0, stream>>>(
        ghistp, logits, gcnt, srid_p, sel_t, ntot);
    kprep_scatter<<<dim3(64), dim3(256), 0, stream>>>(
        rule_ids, gcnt, perm_p, srid_p);
    kmain<<<dim3(NTILE16), dim3(256), 0, stream>>>(
        x, perm_p, srid_p, ssb, sob, rinf, rof, sel_t, ntot, out);
}